// Round 1
// baseline (1555.722 us; speedup 1.0000x reference)
//
#include <hip/hip_runtime.h>
#include <stdint.h>

// ElmanNLM: B=8, T=256, V=32000, H=256
// out = (log_probs [8,256,32000], h_last [1,8,256]) fp32
#define VOCAB 32000
#define HID   256
#define BATCH 8
#define SEQ   256
#define MTOT  2048            // B*T
#define KSPLIT 25
#define KCHUNK 1280           // VOCAB / KSPLIT

typedef __attribute__((ext_vector_type(8))) short  short8;
typedef __attribute__((ext_vector_type(4))) float  floatx4;

__device__ __forceinline__ unsigned short f2bf(float f) {
  unsigned int u = __float_as_uint(f);
  u += 0x7FFFu + ((u >> 16) & 1u);          // RNE
  return (unsigned short)(u >> 16);
}
__device__ __forceinline__ float bf2f(unsigned short b) {
  return __uint_as_float(((unsigned int)b) << 16);
}

typedef const __attribute__((address_space(1))) uint32_t* gcu32p;
typedef __attribute__((address_space(3))) uint32_t*       lu32p;

// async global->LDS, 16B per lane; lds base must be wave-uniform (lane deposits at base + lane*16)
__device__ __forceinline__ void load_lds16(const void* g, void* lds) {
  __builtin_amdgcn_global_load_lds((gcu32p)(uintptr_t)g,
                                   (lu32p)(uint32_t)(uintptr_t)lds, 16, 0, 0);
}

// ---------------- weight conversion kernels ----------------
__global__ void k_conv_split(const float4* __restrict__ in, ushort4* __restrict__ hi,
                             ushort4* __restrict__ lo, int n4) {
  int i = blockIdx.x * 256 + threadIdx.x;
  if (i >= n4) return;
  float4 v = in[i];
  ushort4 h, l;
  h.x = f2bf(v.x); l.x = f2bf(v.x - bf2f(h.x));
  h.y = f2bf(v.y); l.y = f2bf(v.y - bf2f(h.y));
  h.z = f2bf(v.z); l.z = f2bf(v.z - bf2f(h.z));
  h.w = f2bf(v.w); l.w = f2bf(v.w - bf2f(h.w));
  hi[i] = h; lo[i] = l;
}

__global__ void k_conv(const float4* __restrict__ in, ushort4* __restrict__ out, int n4) {
  int i = blockIdx.x * 256 + threadIdx.x;
  if (i >= n4) return;
  float4 v = in[i];
  ushort4 h;
  h.x = f2bf(v.x); h.y = f2bf(v.y); h.z = f2bf(v.z); h.w = f2bf(v.w);
  out[i] = h;
}

// ---------------- Phase A: x_pre partial GEMM (split-K, hi/lo bf16) ----------------
// A: input [2048][32000] fp32 (converted hi/lo in-register while staging)
// B: W_ih hi/lo bf16 [256][32000]  (B^T layout, staged via global_load_lds)
// out: partials [KSPLIT][2048][256] fp32 (in d_out scratch)
// grid (KSPLIT, 16), 512 threads: 8 waves, wave (wr=w>>2, wc=w&3) -> 64x64 of 128x256 tile
__global__ __launch_bounds__(512, 2) void k_gemm_a(
    const float* __restrict__ A, const unsigned short* __restrict__ Bh,
    const unsigned short* __restrict__ Bl, float* __restrict__ part)
{
  __shared__ __align__(16) unsigned short Ah[128*32], Al[128*32];
  __shared__ __align__(16) unsigned short Bhs[256*32], Bls[256*32];
  const int tid = threadIdx.x;
  const int l = tid & 63, w = tid >> 6;
  const int wr = w >> 2, wc = w & 3;
  const int q = l >> 4, c = l & 15;
  const int m0 = blockIdx.y * 128;
  const int kbeg = blockIdx.x * KCHUNK;
  floatx4 acc[4][4] = {};
  for (int k0 = kbeg; k0 < kbeg + KCHUNK; k0 += 32) {
    // stage A fp32 -> hi/lo bf16 (1024 float4 slots)
#pragma unroll
    for (int i = 0; i < 2; ++i) {
      int idx = i*512 + tid;
      int row = idx >> 3, kq = idx & 7;
      const float4 v = *reinterpret_cast<const float4*>(A + (size_t)(m0+row)*VOCAB + k0 + kq*4);
      ushort4 h, lo2;
      h.x = f2bf(v.x); lo2.x = f2bf(v.x - bf2f(h.x));
      h.y = f2bf(v.y); lo2.y = f2bf(v.y - bf2f(h.y));
      h.z = f2bf(v.z); lo2.z = f2bf(v.z - bf2f(h.z));
      h.w = f2bf(v.w); lo2.w = f2bf(v.w - bf2f(h.w));
      *reinterpret_cast<ushort4*>(&Ah[row*32 + kq*4]) = h;
      *reinterpret_cast<ushort4*>(&Al[row*32 + kq*4]) = lo2;
    }
    // stage B (already bf16) via async 16B direct-to-LDS
#pragma unroll
    for (int i = 0; i < 2; ++i) {
      int idx = i*512 + tid;               // tid = w*64 + l  -> lds base wave-uniform
      int row = idx >> 2, seg = idx & 3;
      size_t goff = (size_t)row*(VOCAB*2) + (size_t)(k0 + seg*8)*2;
      char* dsth = (char*)Bhs + (size_t)(i*512 + w*64)*16;
      char* dstl = (char*)Bls + (size_t)(i*512 + w*64)*16;
      load_lds16((const char*)Bh + goff, dsth);
      load_lds16((const char*)Bl + goff, dstl);
    }
    __syncthreads();
    short8 ah[4], al[4], bh[4], bl[4];
#pragma unroll
    for (int mi = 0; mi < 4; ++mi) {
      int r = wr*64 + mi*16 + c;
      ah[mi] = *reinterpret_cast<const short8*>(&Ah[r*32 + q*8]);
      al[mi] = *reinterpret_cast<const short8*>(&Al[r*32 + q*8]);
    }
#pragma unroll
    for (int ni = 0; ni < 4; ++ni) {
      int n = wc*64 + ni*16 + c;
      bh[ni] = *reinterpret_cast<const short8*>(&Bhs[n*32 + q*8]);
      bl[ni] = *reinterpret_cast<const short8*>(&Bls[n*32 + q*8]);
    }
#pragma unroll
    for (int mi = 0; mi < 4; ++mi)
#pragma unroll
      for (int ni = 0; ni < 4; ++ni) {
        acc[mi][ni] = __builtin_amdgcn_mfma_f32_16x16x32_bf16(ah[mi], bh[ni], acc[mi][ni], 0, 0, 0);
        acc[mi][ni] = __builtin_amdgcn_mfma_f32_16x16x32_bf16(ah[mi], bl[ni], acc[mi][ni], 0, 0, 0);
        acc[mi][ni] = __builtin_amdgcn_mfma_f32_16x16x32_bf16(al[mi], bh[ni], acc[mi][ni], 0, 0, 0);
      }
    __syncthreads();
  }
  float* out = part + (size_t)blockIdx.x * (MTOT*HID);
#pragma unroll
  for (int mi = 0; mi < 4; ++mi)
#pragma unroll
    for (int ni = 0; ni < 4; ++ni)
#pragma unroll
      for (int r = 0; r < 4; ++r) {
        int row = m0 + wr*64 + mi*16 + q*4 + r;   // C layout: row=(lane>>4)*4+reg, col=lane&15
        int col = wc*64 + ni*16 + c;
        out[(size_t)row*HID + col] = acc[mi][ni][r];
      }
}

// ---------------- split-K reduce + biases ----------------
__global__ void k_reduce_bias(const float* __restrict__ part, const float* __restrict__ bih,
                              const float* __restrict__ bhh, float* __restrict__ xpre) {
  int i = blockIdx.x * 256 + threadIdx.x;   // grid 2048 -> 524288
  float s = bih[i & 255] + bhh[i & 255];
#pragma unroll
  for (int p = 0; p < KSPLIT; ++p) s += part[(size_t)p * (MTOT*HID) + i];
  xpre[i] = s;
}

// ---------------- Phase B: sequential scan, 1 block, MFMA with W_hh in VGPRs ----------------
// h kept in LDS as bf16 in A-fragment layout [16][256] (rows 8..15 = zero pad)
__global__ __launch_bounds__(256, 1) void k_rnn(
    const float* __restrict__ xpre, const float* __restrict__ h0,
    const float* __restrict__ Whh, unsigned short* __restrict__ hsb,
    float* __restrict__ hlast)
{
  __shared__ __align__(16) unsigned short hA[16*HID];
  __shared__ __align__(16) float xp[2][BATCH*HID];
  const int tid = threadIdx.x;
  const int l = tid & 63, w = tid >> 6;
  const int q = l >> 4, c = l & 15;
  // preload W_hh fragments (B^T form: W[n][k]) -> 128 VGPRs
  short8 bw[4][8];
#pragma unroll
  for (int nt = 0; nt < 4; ++nt) {
    int n = w*64 + nt*16 + c;
#pragma unroll
    for (int kc = 0; kc < 8; ++kc) {
      int k = kc*32 + q*8;
      const float4 v0 = *reinterpret_cast<const float4*>(Whh + n*HID + k);
      const float4 v1 = *reinterpret_cast<const float4*>(Whh + n*HID + k + 4);
      short8 f;
      f[0] = (short)f2bf(v0.x); f[1] = (short)f2bf(v0.y); f[2] = (short)f2bf(v0.z); f[3] = (short)f2bf(v0.w);
      f[4] = (short)f2bf(v1.x); f[5] = (short)f2bf(v1.y); f[6] = (short)f2bf(v1.z); f[7] = (short)f2bf(v1.w);
      bw[nt][kc] = f;
    }
  }
  // init h tile (batch rows 0..7 from h0, rows 8..15 zero) + xp[0]
  for (int i = tid; i < 16*HID; i += 256)
    hA[i] = (i < BATCH*HID) ? f2bf(h0[i]) : (unsigned short)0;
#pragma unroll
  for (int i = 0; i < 2; ++i) {
    int s2 = tid + i*256;
    int b = s2 >> 6, off = (s2 & 63) * 4;
    const float4 v = *reinterpret_cast<const float4*>(xpre + ((size_t)b*SEQ)*HID + off);
    *reinterpret_cast<float4*>(&xp[0][b*HID + off]) = v;
  }
  __syncthreads();
  for (int t = 0; t < SEQ; ++t) {
    const int cur = t & 1, nxt = cur ^ 1;
    float4 pf[2];
    if (t < SEQ-1) {
#pragma unroll
      for (int i = 0; i < 2; ++i) {
        int s2 = tid + i*256;
        int b = s2 >> 6, off = (s2 & 63) * 4;
        pf[i] = *reinterpret_cast<const float4*>(xpre + ((size_t)b*SEQ + t + 1)*HID + off);
      }
    }
    short8 af[8];
#pragma unroll
    for (int kc = 0; kc < 8; ++kc)
      af[kc] = *reinterpret_cast<const short8*>(&hA[c*HID + kc*32 + q*8]);
    floatx4 acc[4] = {};
#pragma unroll
    for (int kc = 0; kc < 8; ++kc)
#pragma unroll
      for (int nt = 0; nt < 4; ++nt)
        acc[nt] = __builtin_amdgcn_mfma_f32_16x16x32_bf16(af[kc], bw[nt][kc], acc[nt], 0, 0, 0);
    __syncthreads();                       // all a-frag reads done before hA rewrite
    if (q < 2) {                           // rows q*4+r < 8 (real batches)
#pragma unroll
      for (int nt = 0; nt < 4; ++nt)
#pragma unroll
        for (int r = 0; r < 4; ++r) {
          int row = q*4 + r;
          int n = w*64 + nt*16 + c;
          float pre = acc[nt][r] + xp[cur][row*HID + n];
          float h = tanhf(pre);
          unsigned short hb = f2bf(h);
          hA[row*HID + n] = hb;                                  // next step's A (k index = n)
          hsb[((size_t)(row*SEQ + t))*HID + n] = hb;             // hs bf16 for Phase C
          if (t == SEQ-1) hlast[row*HID + n] = h;
        }
    }
    if (t < SEQ-1) {
#pragma unroll
      for (int i = 0; i < 2; ++i) {
        int s2 = tid + i*256;
        int b = s2 >> 6, off = (s2 & 63) * 4;
        *reinterpret_cast<float4*>(&xp[nxt][b*HID + off]) = pf[i];
      }
    }
    __syncthreads();
  }
}

// ---------------- Phase C: logits GEMM + bias + per-tile softmax stats ----------------
// grid (250, 16), 256 threads; wave (wr=w>>1, wc=w&1) -> 64x64 of 128x128 tile
template <bool BBF16>
__global__ __launch_bounds__(256, 2) void k_gemm_c(
    const unsigned short* __restrict__ Ahs,   // hs bf16 [2048][256]
    const unsigned short* __restrict__ Bw,    // W_fc bf16 [32000][256] (if BBF16)
    const float* __restrict__ Wfc32,          // W_fc fp32 (if !BBF16)
    const float* __restrict__ bfc,
    float* __restrict__ logits,               // d_out [2048][32000]
    float2* __restrict__ stats)               // [2048][250] (max, sumexp)
{
  __shared__ __align__(16) unsigned short As[128*32], Bs[128*32];
  __shared__ float biasLds[128];
  __shared__ float2 sred[128][2];
  const int tid = threadIdx.x;
  const int l = tid & 63, w = tid >> 6;
  const int wr = w >> 1, wc = w & 1;
  const int q = l >> 4, c = l & 15;
  const int n0 = blockIdx.x * 128, m0 = blockIdx.y * 128;
  if (tid < 128) biasLds[tid] = bfc[n0 + tid];
  floatx4 acc[4][4] = {};
  for (int kc = 0; kc < 8; ++kc) {
#pragma unroll
    for (int i = 0; i < 2; ++i) {           // A: 512 slots of 16B
      int idx = i*256 + tid;
      int row = idx >> 2, seg = idx & 3;
      load_lds16((const char*)Ahs + (size_t)(m0+row)*(HID*2) + kc*64 + seg*16,
                 (char*)As + (size_t)(i*256 + w*64)*16);
    }
    if (BBF16) {
#pragma unroll
      for (int i = 0; i < 2; ++i) {
        int idx = i*256 + tid;
        int row = idx >> 2, seg = idx & 3;
        load_lds16((const char*)Bw + (size_t)(n0+row)*(HID*2) + kc*64 + seg*16,
                   (char*)Bs + (size_t)(i*256 + w*64)*16);
      }
    } else {
#pragma unroll
      for (int i = 0; i < 4; ++i) {         // 1024 float4 slots, convert in-register
        int idx = i*256 + tid;
        int row = idx >> 3, kq = idx & 7;
        const float4 v = *reinterpret_cast<const float4*>(Wfc32 + (size_t)(n0+row)*HID + kc*32 + kq*4);
        ushort4 h;
        h.x = f2bf(v.x); h.y = f2bf(v.y); h.z = f2bf(v.z); h.w = f2bf(v.w);
        *reinterpret_cast<ushort4*>(&Bs[row*32 + kq*4]) = h;
      }
    }
    __syncthreads();
    short8 af[4], bfr[4];
#pragma unroll
    for (int mi = 0; mi < 4; ++mi)
      af[mi] = *reinterpret_cast<const short8*>(&As[(wr*64 + mi*16 + c)*32 + q*8]);
#pragma unroll
    for (int ni = 0; ni < 4; ++ni)
      bfr[ni] = *reinterpret_cast<const short8*>(&Bs[(wc*64 + ni*16 + c)*32 + q*8]);
#pragma unroll
    for (int mi = 0; mi < 4; ++mi)
#pragma unroll
      for (int ni = 0; ni < 4; ++ni)
        acc[mi][ni] = __builtin_amdgcn_mfma_f32_16x16x32_bf16(af[mi], bfr[ni], acc[mi][ni], 0, 0, 0);
    __syncthreads();
  }
  // epilogue: bias add, store logits, per-row tile stats
#pragma unroll
  for (int mi = 0; mi < 4; ++mi) {
#pragma unroll
    for (int r = 0; r < 4; ++r) {
      int rowl = wr*64 + mi*16 + q*4 + r;
      float v[4];
#pragma unroll
      for (int ni = 0; ni < 4; ++ni) {
        int coll = wc*64 + ni*16 + c;
        v[ni] = acc[mi][ni][r] + biasLds[coll];
        logits[(size_t)(m0+rowl)*VOCAB + n0 + coll] = v[ni];
      }
      float mx = fmaxf(fmaxf(v[0], v[1]), fmaxf(v[2], v[3]));
#pragma unroll
      for (int d = 1; d < 16; d <<= 1) mx = fmaxf(mx, __shfl_xor(mx, d));
      float s = __expf(v[0]-mx) + __expf(v[1]-mx) + __expf(v[2]-mx) + __expf(v[3]-mx);
#pragma unroll
      for (int d = 1; d < 16; d <<= 1) s += __shfl_xor(s, d);
      if (c == 0) sred[rowl][wc] = make_float2(mx, s);
    }
  }
  __syncthreads();
  if (tid < 128) {
    float2 p0 = sred[tid][0], p1 = sred[tid][1];
    float M = fmaxf(p0.x, p1.x);
    float S = p0.y * __expf(p0.x - M) + p1.y * __expf(p1.x - M);
    stats[(size_t)(m0 + tid)*250 + blockIdx.x] = make_float2(M, S);
  }
}

// ---------------- softmax stat combine ----------------
__global__ void k_lse(const float2* __restrict__ stats, float* __restrict__ lse) {
  int row = blockIdx.x, tid = threadIdx.x;
  float m = -3.4e38f, s = 0.f;
  if (tid < 250) { float2 p = stats[(size_t)row*250 + tid]; m = p.x; s = p.y; }
  float M = m;
#pragma unroll
  for (int d = 1; d < 64; d <<= 1) M = fmaxf(M, __shfl_xor(M, d));
  __shared__ float wm[4], wsum[4];
  int w = tid >> 6, l = tid & 63;
  if (l == 0) wm[w] = M;
  __syncthreads();
  float gM = fmaxf(fmaxf(wm[0], wm[1]), fmaxf(wm[2], wm[3]));
  float sp = (tid < 250) ? s * __expf(m - gM) : 0.f;
#pragma unroll
  for (int d = 1; d < 64; d <<= 1) sp += __shfl_xor(sp, d);
  if (l == 0) wsum[w] = sp;
  __syncthreads();
  if (tid == 0) lse[row] = gM + logf(wsum[0] + wsum[1] + wsum[2] + wsum[3]);
}

// ---------------- in-place normalize ----------------
__global__ void k_norm(float* __restrict__ out, const float* __restrict__ lse) {
  int row = blockIdx.x;
  float L = lse[row];
  float4* p = reinterpret_cast<float4*>(out + (size_t)row * VOCAB);
  for (int i = threadIdx.x; i < VOCAB/4; i += 256) {
    float4 v = p[i];
    v.x -= L; v.y -= L; v.z -= L; v.w -= L;
    p[i] = v;
  }
}

extern "C" void kernel_launch(void* const* d_in, const int* in_sizes, int n_in,
                              void* d_out, int out_size, void* d_ws, size_t ws_size,
                              hipStream_t stream) {
  const float* input = (const float*)d_in[0];
  const float* h0    = (const float*)d_in[1];
  const float* Wih   = (const float*)d_in[2];
  const float* Whh   = (const float*)d_in[3];
  const float* bih   = (const float*)d_in[4];
  const float* bhh   = (const float*)d_in[5];
  const float* Wfc   = (const float*)d_in[6];
  const float* bfc   = (const float*)d_in[7];
  float* out = (float*)d_out;

  // d_out scratch (dead before logits written): partials [25][2048][256], W_ih hi/lo bf16
  float* part            = out;                                          // 52,428,800 B
  unsigned short* wih_hi = (unsigned short*)((char*)d_out + 52428800);   // 16,384,000 B
  unsigned short* wih_lo = (unsigned short*)((char*)d_out + 68812800);   // 16,384,000 B
  float* hlast           = out + 65536000;                               // output 1 tail

  char* ws = (char*)d_ws;
  const bool big = ws_size >= (size_t)23633920;   // room for W_fc bf16?
  unsigned short* wfc_bf;
  float* xpre; unsigned short* hsb; float2* stats; float* lse;
  if (big) {
    wfc_bf = (unsigned short*)ws;                  // 16,384,000 B
    xpre   = (float*)(ws + 16384000);              //  2,097,152 B
    hsb    = (unsigned short*)(ws + 18481152);     //  1,048,576 B
    stats  = (float2*)(ws + 19529728);             //  4,096,000 B
    lse    = (float*)(ws + 23625728);              //      8,192 B
  } else {                                         // compact: 7.25 MB, Phase C stages fp32 B
    wfc_bf = nullptr;
    xpre   = (float*)ws;
    hsb    = (unsigned short*)(ws + 2097152);
    stats  = (float2*)(ws + 3145728);
    lse    = (float*)(ws + 7241728);
  }

  k_conv_split<<<8000, 256, 0, stream>>>((const float4*)Wih, (ushort4*)wih_hi, (ushort4*)wih_lo, 2048000);
  if (big)
    k_conv<<<8000, 256, 0, stream>>>((const float4*)Wfc, (ushort4*)wfc_bf, 2048000);
  k_gemm_a<<<dim3(KSPLIT, 16), 512, 0, stream>>>(input, wih_hi, wih_lo, part);
  k_reduce_bias<<<2048, 256, 0, stream>>>(part, bih, bhh, xpre);
  k_rnn<<<1, 256, 0, stream>>>(xpre, h0, Whh, hsb, hlast);
  if (big)
    k_gemm_c<true><<<dim3(250, 16), 256, 0, stream>>>(hsb, wfc_bf, nullptr, bfc, out, stats);
  else
    k_gemm_c<false><<<dim3(250, 16), 256, 0, stream>>>(hsb, nullptr, Wfc, bfc, out, stats);
  k_lse<<<2048, 256, 0, stream>>>(stats, lse);
  k_norm<<<2048, 256, 0, stream>>>(out, lse);
}

// Round 2
// 1003.317 us; speedup vs baseline: 1.5506x; 1.5506x over previous
//
#include <hip/hip_runtime.h>
#include <stdint.h>

// ElmanNLM: B=8, T=256, V=32000, H=256
// out = (log_probs [8,256,32000], h_last [1,8,256]) fp32
#define VOCAB 32000
#define HID   256
#define BATCH 8
#define SEQ   256
#define MTOT  2048            // B*T
#define KSPLIT 25
#define KCHUNK 1280           // VOCAB / KSPLIT

typedef __attribute__((ext_vector_type(8))) short  short8;
typedef __attribute__((ext_vector_type(4))) float  floatx4;

__device__ __forceinline__ unsigned short f2bf(float f) {
  unsigned int u = __float_as_uint(f);
  u += 0x7FFFu + ((u >> 16) & 1u);          // RNE
  return (unsigned short)(u >> 16);
}
__device__ __forceinline__ float bf2f(unsigned short b) {
  return __uint_as_float(((unsigned int)b) << 16);
}

// tanh(x) = 1 - 2/(1+e^{2x}); saturates correctly (e->0 => -1, e->inf => 1)
__device__ __forceinline__ float fast_tanh(float x) {
  float e = __expf(2.f * x);
  return 1.f - 2.f * __builtin_amdgcn_rcpf(1.f + e);
}

typedef const __attribute__((address_space(1))) uint32_t* gcu32p;
typedef __attribute__((address_space(3))) uint32_t*       lu32p;

// async global->LDS, 16B per lane; lds base must be wave-uniform (lane deposits at base + lane*16)
__device__ __forceinline__ void load_lds16(const void* g, void* lds) {
  __builtin_amdgcn_global_load_lds((gcu32p)(uintptr_t)g,
                                   (lu32p)(uint32_t)(uintptr_t)lds, 16, 0, 0);
}

// barrier that does NOT drain vmcnt (global stores may stay in flight).
// lgkmcnt(0) orders LDS writes/reads; asm memory clobber pins compiler ordering.
__device__ __forceinline__ void lds_barrier() {
  __asm__ __volatile__("s_waitcnt lgkmcnt(0)\n\ts_barrier" ::: "memory");
}

// ---------------- weight conversion kernels ----------------
__global__ void k_conv_split(const float4* __restrict__ in, ushort4* __restrict__ hi,
                             ushort4* __restrict__ lo, int n4) {
  int i = blockIdx.x * 256 + threadIdx.x;
  if (i >= n4) return;
  float4 v = in[i];
  ushort4 h, l;
  h.x = f2bf(v.x); l.x = f2bf(v.x - bf2f(h.x));
  h.y = f2bf(v.y); l.y = f2bf(v.y - bf2f(h.y));
  h.z = f2bf(v.z); l.z = f2bf(v.z - bf2f(h.z));
  h.w = f2bf(v.w); l.w = f2bf(v.w - bf2f(h.w));
  hi[i] = h; lo[i] = l;
}

__global__ void k_conv(const float4* __restrict__ in, ushort4* __restrict__ out, int n4) {
  int i = blockIdx.x * 256 + threadIdx.x;
  if (i >= n4) return;
  float4 v = in[i];
  ushort4 h;
  h.x = f2bf(v.x); h.y = f2bf(v.y); h.z = f2bf(v.z); h.w = f2bf(v.w);
  out[i] = h;
}

// ---------------- Phase A: x_pre partial GEMM (split-K, hi/lo bf16) ----------------
__global__ __launch_bounds__(512, 2) void k_gemm_a(
    const float* __restrict__ A, const unsigned short* __restrict__ Bh,
    const unsigned short* __restrict__ Bl, float* __restrict__ part)
{
  __shared__ __align__(16) unsigned short Ah[128*32], Al[128*32];
  __shared__ __align__(16) unsigned short Bhs[256*32], Bls[256*32];
  const int tid = threadIdx.x;
  const int l = tid & 63, w = tid >> 6;
  const int wr = w >> 2, wc = w & 3;
  const int q = l >> 4, c = l & 15;
  const int m0 = blockIdx.y * 128;
  const int kbeg = blockIdx.x * KCHUNK;
  floatx4 acc[4][4] = {};
  for (int k0 = kbeg; k0 < kbeg + KCHUNK; k0 += 32) {
#pragma unroll
    for (int i = 0; i < 2; ++i) {
      int idx = i*512 + tid;
      int row = idx >> 3, kq = idx & 7;
      const float4 v = *reinterpret_cast<const float4*>(A + (size_t)(m0+row)*VOCAB + k0 + kq*4);
      ushort4 h, lo2;
      h.x = f2bf(v.x); lo2.x = f2bf(v.x - bf2f(h.x));
      h.y = f2bf(v.y); lo2.y = f2bf(v.y - bf2f(h.y));
      h.z = f2bf(v.z); lo2.z = f2bf(v.z - bf2f(h.z));
      h.w = f2bf(v.w); lo2.w = f2bf(v.w - bf2f(h.w));
      *reinterpret_cast<ushort4*>(&Ah[row*32 + kq*4]) = h;
      *reinterpret_cast<ushort4*>(&Al[row*32 + kq*4]) = lo2;
    }
#pragma unroll
    for (int i = 0; i < 2; ++i) {
      int idx = i*512 + tid;
      int row = idx >> 2, seg = idx & 3;
      size_t goff = (size_t)row*(VOCAB*2) + (size_t)(k0 + seg*8)*2;
      char* dsth = (char*)Bhs + (size_t)(i*512 + w*64)*16;
      char* dstl = (char*)Bls + (size_t)(i*512 + w*64)*16;
      load_lds16((const char*)Bh + goff, dsth);
      load_lds16((const char*)Bl + goff, dstl);
    }
    __syncthreads();
    short8 ah[4], al[4], bh[4], bl[4];
#pragma unroll
    for (int mi = 0; mi < 4; ++mi) {
      int r = wr*64 + mi*16 + c;
      ah[mi] = *reinterpret_cast<const short8*>(&Ah[r*32 + q*8]);
      al[mi] = *reinterpret_cast<const short8*>(&Al[r*32 + q*8]);
    }
#pragma unroll
    for (int ni = 0; ni < 4; ++ni) {
      int n = wc*64 + ni*16 + c;
      bh[ni] = *reinterpret_cast<const short8*>(&Bhs[n*32 + q*8]);
      bl[ni] = *reinterpret_cast<const short8*>(&Bls[n*32 + q*8]);
    }
#pragma unroll
    for (int mi = 0; mi < 4; ++mi)
#pragma unroll
      for (int ni = 0; ni < 4; ++ni) {
        acc[mi][ni] = __builtin_amdgcn_mfma_f32_16x16x32_bf16(ah[mi], bh[ni], acc[mi][ni], 0, 0, 0);
        acc[mi][ni] = __builtin_amdgcn_mfma_f32_16x16x32_bf16(ah[mi], bl[ni], acc[mi][ni], 0, 0, 0);
        acc[mi][ni] = __builtin_amdgcn_mfma_f32_16x16x32_bf16(al[mi], bh[ni], acc[mi][ni], 0, 0, 0);
      }
    __syncthreads();
  }
  float* out = part + (size_t)blockIdx.x * (MTOT*HID);
#pragma unroll
  for (int mi = 0; mi < 4; ++mi)
#pragma unroll
    for (int ni = 0; ni < 4; ++ni)
#pragma unroll
      for (int r = 0; r < 4; ++r) {
        int row = m0 + wr*64 + mi*16 + q*4 + r;
        int col = wc*64 + ni*16 + c;
        out[(size_t)row*HID + col] = acc[mi][ni][r];
      }
}

// ---------------- split-K reduce + biases ----------------
__global__ void k_reduce_bias(const float* __restrict__ part, const float* __restrict__ bih,
                              const float* __restrict__ bhh, float* __restrict__ xpre) {
  int i = blockIdx.x * 256 + threadIdx.x;
  float s = bih[i & 255] + bhh[i & 255];
#pragma unroll
  for (int p = 0; p < KSPLIT; ++p) s += part[(size_t)p * (MTOT*HID) + i];
  xpre[i] = s;
}

// ---------------- Phase B: sequential scan, 1 block, MFMA with W_hh in VGPRs ----------------
// hA physical layout: granule-chunk order so a-frag ds_read_b128 is 64 consecutive
// 16B chunks per wave (conflict-free). Element (m,k):
//   idx_us = (k>>5)*512 + ((k>>3)&3)*128 + m*8 + (k&7)
__device__ __forceinline__ int hA_idx(int m, int k) {
  return ((k >> 5) << 9) + (((k >> 3) & 3) << 7) + (m << 3) + (k & 7);
}

__global__ __launch_bounds__(256, 1) void k_rnn(
    const float* __restrict__ xpre, const float* __restrict__ h0,
    const float* __restrict__ Whh, unsigned short* __restrict__ hsb,
    float* __restrict__ hlast)
{
  __shared__ __align__(16) unsigned short hA[16*HID];
  __shared__ __align__(16) float xp[2][BATCH*HID];
  const int tid = threadIdx.x;
  const int l = tid & 63, w = tid >> 6;
  const int q = l >> 4, c = l & 15;
  // preload W_hh fragments (B^T form: W[n][k]) -> 128 VGPRs
  short8 bw[4][8];
#pragma unroll
  for (int nt = 0; nt < 4; ++nt) {
    int n = w*64 + nt*16 + c;
#pragma unroll
    for (int kc = 0; kc < 8; ++kc) {
      int k = kc*32 + q*8;
      const float4 v0 = *reinterpret_cast<const float4*>(Whh + n*HID + k);
      const float4 v1 = *reinterpret_cast<const float4*>(Whh + n*HID + k + 4);
      short8 f;
      f[0] = (short)f2bf(v0.x); f[1] = (short)f2bf(v0.y); f[2] = (short)f2bf(v0.z); f[3] = (short)f2bf(v0.w);
      f[4] = (short)f2bf(v1.x); f[5] = (short)f2bf(v1.y); f[6] = (short)f2bf(v1.z); f[7] = (short)f2bf(v1.w);
      bw[nt][kc] = f;
    }
  }
  // init hA (rows 0..7 from h0, rows 8..15 zero), chunk layout
  for (int idx = tid; idx < 16*HID; idx += 256) {
    int m = idx >> 8, k = idx & 255;
    hA[hA_idx(m, k)] = (m < BATCH) ? f2bf(h0[m*HID + k]) : (unsigned short)0;
  }
#pragma unroll
  for (int i = 0; i < 2; ++i) {
    int s2 = tid + i*256;
    int b = s2 >> 6, off = (s2 & 63) * 4;
    const float4 v = *reinterpret_cast<const float4*>(xpre + ((size_t)b*SEQ)*HID + off);
    *reinterpret_cast<float4*>(&xp[0][b*HID + off]) = v;
  }
  __syncthreads();
  const int row_base = (q & 1) * 4 + (q >> 1) * 2;
  for (int t = 0; t < SEQ; ++t) {
    const int cur = t & 1, nxt = cur ^ 1;
    float4 pf[2];
    if (t < SEQ-1) {
#pragma unroll
      for (int i = 0; i < 2; ++i) {
        int s2 = tid + i*256;
        int b = s2 >> 6, off = (s2 & 63) * 4;
        pf[i] = *reinterpret_cast<const float4*>(xpre + ((size_t)b*SEQ + t + 1)*HID + off);
      }
    }
    // a-frags: wave reads 64 consecutive 16B chunks at kc*1024 + l*16 bytes
    short8 af[8];
#pragma unroll
    for (int kc = 0; kc < 8; ++kc)
      af[kc] = *reinterpret_cast<const short8*>(&hA[kc*512 + l*8]);
    floatx4 acc[4] = {};
#pragma unroll
    for (int kc = 0; kc < 8; ++kc)
#pragma unroll
      for (int nt = 0; nt < 4; ++nt)
        acc[nt] = __builtin_amdgcn_mfma_f32_16x16x32_bf16(af[kc], bw[nt][kc], acc[nt], 0, 0, 0);
    lds_barrier();                        // a-frag reads done in all waves; hA rewrite safe
    // redistribute rows 0..7 over all 4 q-groups: q=0->rows{0,1}, q=1->{4,5}, q=2->{2,3}, q=3->{6,7}
#pragma unroll
    for (int nt = 0; nt < 4; ++nt) {
#pragma unroll
      for (int j = 0; j < 2; ++j) {
        float shuf = __shfl_xor(acc[nt][2+j], 32);
        float v = (q < 2) ? acc[nt][j] : shuf;
        int row = row_base + j;
        int n = w*64 + nt*16 + c;
        float pre = v + xp[cur][row*HID + n];
        float h = fast_tanh(pre);
        unsigned short hb = f2bf(h);
        hA[hA_idx(row, n)] = hb;                          // next step's A
        hsb[((size_t)(row*SEQ + t))*HID + n] = hb;        // hs bf16 for Phase C (never read here)
        if (t == SEQ-1) hlast[row*HID + n] = h;
      }
    }
    if (t < SEQ-1) {
#pragma unroll
      for (int i = 0; i < 2; ++i) {
        int s2 = tid + i*256;
        int b = s2 >> 6, off = (s2 & 63) * 4;
        *reinterpret_cast<float4*>(&xp[nxt][b*HID + off]) = pf[i];
      }
    }
    lds_barrier();                        // hA/xp writes visible; global stores stay in flight
  }
}

// ---------------- Phase C: logits GEMM + bias + per-tile softmax stats ----------------
template <bool BBF16>
__global__ __launch_bounds__(256, 2) void k_gemm_c(
    const unsigned short* __restrict__ Ahs,
    const unsigned short* __restrict__ Bw,
    const float* __restrict__ Wfc32,
    const float* __restrict__ bfc,
    float* __restrict__ logits,
    float2* __restrict__ stats)
{
  __shared__ __align__(16) unsigned short As[128*32], Bs[128*32];
  __shared__ float biasLds[128];
  __shared__ float2 sred[128][2];
  const int tid = threadIdx.x;
  const int l = tid & 63, w = tid >> 6;
  const int wr = w >> 1, wc = w & 1;
  const int q = l >> 4, c = l & 15;
  const int n0 = blockIdx.x * 128, m0 = blockIdx.y * 128;
  if (tid < 128) biasLds[tid] = bfc[n0 + tid];
  floatx4 acc[4][4] = {};
  for (int kc = 0; kc < 8; ++kc) {
#pragma unroll
    for (int i = 0; i < 2; ++i) {
      int idx = i*256 + tid;
      int row = idx >> 2, seg = idx & 3;
      load_lds16((const char*)Ahs + (size_t)(m0+row)*(HID*2) + kc*64 + seg*16,
                 (char*)As + (size_t)(i*256 + w*64)*16);
    }
    if (BBF16) {
#pragma unroll
      for (int i = 0; i < 2; ++i) {
        int idx = i*256 + tid;
        int row = idx >> 2, seg = idx & 3;
        load_lds16((const char*)Bw + (size_t)(n0+row)*(HID*2) + kc*64 + seg*16,
                   (char*)Bs + (size_t)(i*256 + w*64)*16);
      }
    } else {
#pragma unroll
      for (int i = 0; i < 4; ++i) {
        int idx = i*256 + tid;
        int row = idx >> 3, kq = idx & 7;
        const float4 v = *reinterpret_cast<const float4*>(Wfc32 + (size_t)(n0+row)*HID + kc*32 + kq*4);
        ushort4 h;
        h.x = f2bf(v.x); h.y = f2bf(v.y); h.z = f2bf(v.z); h.w = f2bf(v.w);
        *reinterpret_cast<ushort4*>(&Bs[row*32 + kq*4]) = h;
      }
    }
    __syncthreads();
    short8 af[4], bfr[4];
#pragma unroll
    for (int mi = 0; mi < 4; ++mi)
      af[mi] = *reinterpret_cast<const short8*>(&As[(wr*64 + mi*16 + c)*32 + q*8]);
#pragma unroll
    for (int ni = 0; ni < 4; ++ni)
      bfr[ni] = *reinterpret_cast<const short8*>(&Bs[(wc*64 + ni*16 + c)*32 + q*8]);
#pragma unroll
    for (int mi = 0; mi < 4; ++mi)
#pragma unroll
      for (int ni = 0; ni < 4; ++ni)
        acc[mi][ni] = __builtin_amdgcn_mfma_f32_16x16x32_bf16(af[mi], bfr[ni], acc[mi][ni], 0, 0, 0);
    __syncthreads();
  }
#pragma unroll
  for (int mi = 0; mi < 4; ++mi) {
#pragma unroll
    for (int r = 0; r < 4; ++r) {
      int rowl = wr*64 + mi*16 + q*4 + r;
      float v[4];
#pragma unroll
      for (int ni = 0; ni < 4; ++ni) {
        int coll = wc*64 + ni*16 + c;
        v[ni] = acc[mi][ni][r] + biasLds[coll];
        logits[(size_t)(m0+rowl)*VOCAB + n0 + coll] = v[ni];
      }
      float mx = fmaxf(fmaxf(v[0], v[1]), fmaxf(v[2], v[3]));
#pragma unroll
      for (int d = 1; d < 16; d <<= 1) mx = fmaxf(mx, __shfl_xor(mx, d));
      float s = __expf(v[0]-mx) + __expf(v[1]-mx) + __expf(v[2]-mx) + __expf(v[3]-mx);
#pragma unroll
      for (int d = 1; d < 16; d <<= 1) s += __shfl_xor(s, d);
      if (c == 0) sred[rowl][wc] = make_float2(mx, s);
    }
  }
  __syncthreads();
  if (tid < 128) {
    float2 p0 = sred[tid][0], p1 = sred[tid][1];
    float M = fmaxf(p0.x, p1.x);
    float S = p0.y * __expf(p0.x - M) + p1.y * __expf(p1.x - M);
    stats[(size_t)(m0 + tid)*250 + blockIdx.x] = make_float2(M, S);
  }
}

// ---------------- softmax stat combine ----------------
__global__ void k_lse(const float2* __restrict__ stats, float* __restrict__ lse) {
  int row = blockIdx.x, tid = threadIdx.x;
  float m = -3.4e38f, s = 0.f;
  if (tid < 250) { float2 p = stats[(size_t)row*250 + tid]; m = p.x; s = p.y; }
  float M = m;
#pragma unroll
  for (int d = 1; d < 64; d <<= 1) M = fmaxf(M, __shfl_xor(M, d));
  __shared__ float wm[4], wsum[4];
  int w = tid >> 6, l = tid & 63;
  if (l == 0) wm[w] = M;
  __syncthreads();
  float gM = fmaxf(fmaxf(wm[0], wm[1]), fmaxf(wm[2], wm[3]));
  float sp = (tid < 250) ? s * __expf(m - gM) : 0.f;
#pragma unroll
  for (int d = 1; d < 64; d <<= 1) sp += __shfl_xor(sp, d);
  if (l == 0) wsum[w] = sp;
  __syncthreads();
  if (tid == 0) lse[row] = gM + logf(wsum[0] + wsum[1] + wsum[2] + wsum[3]);
}

// ---------------- in-place normalize ----------------
__global__ void k_norm(float* __restrict__ out, const float* __restrict__ lse) {
  int row = blockIdx.x;
  float L = lse[row];
  float4* p = reinterpret_cast<float4*>(out + (size_t)row * VOCAB);
  for (int i = threadIdx.x; i < VOCAB/4; i += 256) {
    float4 v = p[i];
    v.x -= L; v.y -= L; v.z -= L; v.w -= L;
    p[i] = v;
  }
}

extern "C" void kernel_launch(void* const* d_in, const int* in_sizes, int n_in,
                              void* d_out, int out_size, void* d_ws, size_t ws_size,
                              hipStream_t stream) {
  const float* input = (const float*)d_in[0];
  const float* h0    = (const float*)d_in[1];
  const float* Wih   = (const float*)d_in[2];
  const float* Whh   = (const float*)d_in[3];
  const float* bih   = (const float*)d_in[4];
  const float* bhh   = (const float*)d_in[5];
  const float* Wfc   = (const float*)d_in[6];
  const float* bfc   = (const float*)d_in[7];
  float* out = (float*)d_out;

  float* part            = out;
  unsigned short* wih_hi = (unsigned short*)((char*)d_out + 52428800);
  unsigned short* wih_lo = (unsigned short*)((char*)d_out + 68812800);
  float* hlast           = out + 65536000;

  char* ws = (char*)d_ws;
  const bool big = ws_size >= (size_t)23633920;
  unsigned short* wfc_bf;
  float* xpre; unsigned short* hsb; float2* stats; float* lse;
  if (big) {
    wfc_bf = (unsigned short*)ws;
    xpre   = (float*)(ws + 16384000);
    hsb    = (unsigned short*)(ws + 18481152);
    stats  = (float2*)(ws + 19529728);
    lse    = (float*)(ws + 23625728);
  } else {
    wfc_bf = nullptr;
    xpre   = (float*)ws;
    hsb    = (unsigned short*)(ws + 2097152);
    stats  = (float2*)(ws + 3145728);
    lse    = (float*)(ws + 7241728);
  }

  k_conv_split<<<8000, 256, 0, stream>>>((const float4*)Wih, (ushort4*)wih_hi, (ushort4*)wih_lo, 2048000);
  if (big)
    k_conv<<<8000, 256, 0, stream>>>((const float4*)Wfc, (ushort4*)wfc_bf, 2048000);
  k_gemm_a<<<dim3(KSPLIT, 16), 512, 0, stream>>>(input, wih_hi, wih_lo, part);
  k_reduce_bias<<<2048, 256, 0, stream>>>(part, bih, bhh, xpre);
  k_rnn<<<1, 256, 0, stream>>>(xpre, h0, Whh, hsb, hlast);
  if (big)
    k_gemm_c<true><<<dim3(250, 16), 256, 0, stream>>>(hsb, wfc_bf, nullptr, bfc, out, stats);
  else
    k_gemm_c<false><<<dim3(250, 16), 256, 0, stream>>>(hsb, nullptr, Wfc, bfc, out, stats);
  k_lse<<<2048, 256, 0, stream>>>(stats, lse);
  k_norm<<<2048, 256, 0, stream>>>(out, lse);
}